// Round 15
// baseline (439.048 us; speedup 1.0000x reference)
//
#include <hip/hip_runtime.h>
#include <cstdint>
#include <cstddef>

// B=1, S=4096, HIDDEN=2048, HEADS=16, KVH=4, HD=128, CHUNK=1024.
// R21: rope fused into gemm1 epilogue. Each gemm1 block's 128-col span = one
// head, so rope pairs (d, d+64) are intra-block; remapping wave->B-frags to
// {(w&1)*2,+1,+4,+5} makes them intra-LANE (same l15, jl and jl+2). Rope is
// then a per-lane fp32 rotation on acc before the bf16 store (Q/K blocks
// y<20 only; V unchanged). rope_vt shrinks to V-transpose only (512 blocks).
// Saves ~40MB rope RMW traffic + a launch; rope math verbatim from the
// verified kernel; accuracy improves (one bf16 rounding, not two).
// gemm2 stays gemm_bt64 (R20, equal-best). All sync structures untouched.
// BANNED/null: T13 (raced), setprio (null), attn KVBLK=32 (regressed),
// counted-vmcnt mid-fence (raced), prep fusion (noise).
//
// ws arena (bytes), liveness overlays:
//   part  @ 0          41,943,040   (overlays Xbf@0 16MB + Wt@16MB 12.6MB)
//   QKV   @ 41,943,040 25,165,824   ([4096][3072]: Q | K | V bf16)
//     attn @ 41,943,040 16,777,216  (overlay after partials done)
//   Vt    @ 67,108,864  4,194,304   ([kvh][128][4096] bf16)
//   ml    @ 71,303,168  1,310,720   (fp32 m,l per q-row per partial)
//   Wot   @ 72,613,888  8,388,608
//   total 81,002,496 (~77.3 MB)

typedef unsigned short u16;
typedef unsigned int u32;
typedef float f32x4 __attribute__((ext_vector_type(4)));
typedef __bf16 bf16x8 __attribute__((ext_vector_type(8)));

__device__ __forceinline__ u16 f2bf(float f) {
    union { float f; u32 u; } v; v.f = f;
    u32 u = v.u;
    u += 0x7fffu + ((u >> 16) & 1u);
    return (u16)(u >> 16);
}
__device__ __forceinline__ float bf2f(u16 b) {
    union { u32 u; float f; } v; v.u = ((u32)b) << 16;
    return v.f;
}
__device__ __forceinline__ u16 f2h(float f) {
    union { _Float16 h; u16 u; } v; v.h = (_Float16)f; return v.u;
}
__device__ __forceinline__ float h2f(u16 u) {
    union { u16 u; _Float16 h; } v; v.u = u; return (float)v.h;
}
// packed bf16 pair via native casts (compiler emits v_cvt_pk_bf16_f32, RNE)
__device__ __forceinline__ u32 pkbf(float lo, float hi) {
    union { __bf16 h[2]; u32 u; } v;
    v.h[0] = (__bf16)lo; v.h[1] = (__bf16)hi;
    return v.u;
}
// v_exp_f32 computes 2^x (single HW instruction; ISA §3)
__device__ __forceinline__ float exp2_hw(float x) {
    float r;
    asm("v_exp_f32 %0, %1" : "=v"(r) : "v"(x));
    return r;
}

__device__ __forceinline__ void load16_to_lds(const void* g, void* l) {
    __builtin_amdgcn_global_load_lds((const __attribute__((address_space(1))) u32*)g,
                                     (__attribute__((address_space(3))) u32*)l,
                                     16, 0, 0);
}

// Explicit pipeline fence: drain this wave's vmem (glds) + lds ops, then
// block barrier. sched_barrier(0) on both sides: nothing moves across.
#define PIPE_FENCE() do {                                        \
    __builtin_amdgcn_sched_barrier(0);                           \
    asm volatile("s_waitcnt vmcnt(0) lgkmcnt(0)" ::: "memory");  \
    __builtin_amdgcn_sched_barrier(0);                           \
    __builtin_amdgcn_s_barrier();                                \
    __builtin_amdgcn_sched_barrier(0);                           \
} while (0)

#define MFMA16(a, b, c) __builtin_amdgcn_mfma_f32_16x16x32_bf16((a), (b), (c), 0, 0, 0)

// ---------------------------------------------------------------- convert X
__global__ __launch_bounds__(256) void convert_f32_bf16(const float* __restrict__ X,
                                                        u16* __restrict__ Y) {
    const int base = (blockIdx.x * 1024 + threadIdx.x) * 4;
#pragma unroll
    for (int k = 0; k < 4; ++k) {
        const int i = base + k * 1024;
        const float4 v = *(const float4*)(X + i);
        union { u16 s[4]; uint2 u; } pk;
        pk.s[0] = f2bf(v.x); pk.s[1] = f2bf(v.y); pk.s[2] = f2bf(v.z); pk.s[3] = f2bf(v.w);
        *(uint2*)(Y + i) = pk.u;
    }
}

// -------------------------- fused transpose of all 4 weights -> bf16 [N][K]
// grid (80, 32): x<32 Wq->Wt, x<40 Wk->Wt+2048*2048, x<48 Wv->Wt+2560*2048,
// x>=48 Wo->Wot. Source is [K=2048][N] fp32.
__global__ __launch_bounds__(256) void transpose_w4(const float* __restrict__ Wq,
                                                    const float* __restrict__ Wk,
                                                    const float* __restrict__ Wv,
                                                    const float* __restrict__ Wo,
                                                    u16* __restrict__ Wt,
                                                    u16* __restrict__ Wot) {
    __shared__ float tile[64][65];
    const int bx = blockIdx.x;
    const float* W; u16* dst; int N, n0;
    if (bx < 32)      { W = Wq; dst = Wt;                          N = 2048; n0 = bx * 64; }
    else if (bx < 40) { W = Wk; dst = Wt + (size_t)2048 * 2048;    N = 512;  n0 = (bx - 32) * 64; }
    else if (bx < 48) { W = Wv; dst = Wt + (size_t)2560 * 2048;    N = 512;  n0 = (bx - 40) * 64; }
    else              { W = Wo; dst = Wot;                         N = 2048; n0 = (bx - 48) * 64; }
    const int k0 = blockIdx.y * 64;
    const int tc = threadIdx.x & 63, tr = threadIdx.x >> 6;
#pragma unroll
    for (int i = 0; i < 64; i += 4)
        tile[tc][tr + i] = W[(size_t)(k0 + tr + i) * N + n0 + tc];
    __syncthreads();
#pragma unroll
    for (int i = 0; i < 64; i += 4)
        dst[(size_t)(n0 + tr + i) * 2048 + k0 + tc] = f2bf(tile[tr + i][tc]);
}

// ---------------------------------------------------------------- GEMM C = A * Bt^T
__device__ __forceinline__ void store_out(float* p, float v) { *p = v; }
__device__ __forceinline__ void store_out(u16* p, float v) { *p = f2bf(v); }

// R21: gemm1 variant (BK=32, dbuf, count-free fence) with remapped B-frags
// (wave w -> col-frags {(w&1)*2, +1, +4, +5}: each lane holds cols d AND d+64
// for its rows) and fused YaRN rope epilogue on Q/K blocks (blockIdx.y < 20).
__global__ __launch_bounds__(256) void gemm_qkv(const u16* __restrict__ A,
                                                const u16* __restrict__ Bt,
                                                u16* __restrict__ C,
                                                const int* __restrict__ pos_ids,
                                                int M, int N, int K) {
    __shared__ __align__(16) u16 sA[2][4096];   // 8KB each: 8 A-frags (16x32)
    __shared__ __align__(16) u16 sB[2][4096];
    const int t = threadIdx.x;
    const int lane = t & 63, w = t >> 6;
    const int quad = lane >> 4, l15 = lane & 15;
    const int m0 = blockIdx.x << 7, n0 = blockIdx.y << 7;
    const int wr4 = (w >> 1) * 4;
    // remapped B-frag indices: jl=0..3 -> fb = (w&1)*2 + (jl&1) + (jl>>1)*4
    int fb[4];
#pragma unroll
    for (int jl = 0; jl < 4; ++jl)
        fb[jl] = (w & 1) * 2 + (jl & 1) + ((jl >> 1) << 2);
    f32x4 acc[4][4] = {};

    // prologue: stage K-tile 0 into buf[1]
#pragma unroll
    for (int r = 0; r < 2; ++r) {
        const int f = w * 2 + r;
        load16_to_lds(A + (size_t)(m0 + f * 16 + l15) * K + quad * 8, sA[1] + f * 512);
        load16_to_lds(Bt + (size_t)(n0 + f * 16 + l15) * K + quad * 8, sB[1] + f * 512);
    }
    PIPE_FENCE();          // tile 0 landed, visible to all waves

    int cur = 1;
    const int nk = K >> 5;
    for (int kt = 0; kt < nk; ++kt) {
        if (kt + 1 < nk) {
            const int koff = (kt + 1) << 5;
#pragma unroll
            for (int r = 0; r < 2; ++r) {
                const int f = w * 2 + r;
                load16_to_lds(A + (size_t)(m0 + f * 16 + l15) * K + koff + quad * 8,
                              sA[cur ^ 1] + f * 512);
                load16_to_lds(Bt + (size_t)(n0 + f * 16 + l15) * K + koff + quad * 8,
                              sB[cur ^ 1] + f * 512);
            }
        }
        const u16* bA = sA[cur];
        const u16* bB = sB[cur];
        bf16x8 af[4], bb[4];
#pragma unroll
        for (int i = 0; i < 4; ++i)
            af[i] = *(const bf16x8*)(bA + (wr4 + i) * 512 + lane * 8);
#pragma unroll
        for (int j = 0; j < 4; ++j)
            bb[j] = *(const bf16x8*)(bB + fb[j] * 512 + lane * 8);
#pragma unroll
        for (int i = 0; i < 4; ++i)
#pragma unroll
            for (int j = 0; j < 4; ++j)
                acc[i][j] = MFMA16(af[i], bb[j], acc[i][j]);
        if (kt + 1 < nk) {
            PIPE_FENCE();
            cur ^= 1;
        }
    }

    // fused YaRN rope on fp32 acc (Q: y<16, K: 16<=y<20; V blocks skip).
    // Lane's jl=0,1 hold cols d = ((w&1)*2+jl)*16+l15 (<64); jl+2 holds d+64.
    if (blockIdx.y < 20) {
        const float MS = 1.2772588722239781f;
        float invd[2];
#pragma unroll
        for (int pj = 0; pj < 2; ++pj) {
            const float fd = (float)(((w & 1) * 2 + pj) * 16 + l15);
            const float inv_ex = exp2_hw(fd * -0.29580637f);
            const float inv_in = inv_ex * (1.0f / 16.0f);
            const float sm = fminf(fmaxf((fd - 18.0f) * (1.0f / 17.0f), 0.0f), 1.0f);
            invd[pj] = (1.0f - sm) * inv_in + sm * inv_ex;
        }
#pragma unroll
        for (int i = 0; i < 4; ++i)
#pragma unroll
            for (int r = 0; r < 4; ++r) {
                const int row = m0 + (w >> 1) * 64 + i * 16 + quad * 4 + r;
                const float pf = (float)pos_ids[row];
#pragma unroll
                for (int pj = 0; pj < 2; ++pj) {
                    const float ph = pf * invd[pj];
                    const float cs = __cosf(ph) * MS, sn = __sinf(ph) * MS;
                    const float x1 = acc[i][pj][r], x2 = acc[i][pj + 2][r];
                    acc[i][pj][r] = x1 * cs - x2 * sn;
                    acc[i][pj + 2][r] = x2 * cs + x1 * sn;
                }
            }
    }

#pragma unroll
    for (int i = 0; i < 4; ++i)
#pragma unroll
        for (int j = 0; j < 4; ++j) {
            const int row = m0 + (w >> 1) * 64 + i * 16 + quad * 4;
            const int col = n0 + fb[j] * 16 + l15;
#pragma unroll
            for (int r = 0; r < 4; ++r)
                C[(size_t)(row + r) * N + col] = f2bf(acc[i][j][r]);
        }
}

// R20 variant: BK=64, double-buffered (2x16KB per matrix = 64KB LDS -> 2 blk/CU),
// same prefetch + count-free fence. For gemm2 (grid 512 = exactly 2/CU).
template <typename OutT>
__global__ __launch_bounds__(256, 2) void gemm_bt64(const u16* __restrict__ A,
                                                    const u16* __restrict__ Bt,
                                                    OutT* __restrict__ C,
                                                    int M, int N, int K) {
    __shared__ __align__(16) u16 sA[2][8192];   // 16KB each: 16 A-frags (16x32)
    __shared__ __align__(16) u16 sB[2][8192];
    const int t = threadIdx.x;
    const int lane = t & 63, w = t >> 6;
    const int quad = lane >> 4, l15 = lane & 15;
    const int m0 = blockIdx.x << 7, n0 = blockIdx.y << 7;
    const int wr4 = (w >> 1) * 4, wc4 = (w & 1) * 4;
    f32x4 acc[4][4] = {};

    // prologue: stage K-tile 0 (64 wide) into buf[1]
#pragma unroll
    for (int r = 0; r < 2; ++r) {
        const int f = w * 2 + r;
#pragma unroll
        for (int kc = 0; kc < 2; ++kc) {
            load16_to_lds(A + (size_t)(m0 + f * 16 + l15) * K + kc * 32 + quad * 8,
                          sA[1] + (f * 2 + kc) * 512);
            load16_to_lds(Bt + (size_t)(n0 + f * 16 + l15) * K + kc * 32 + quad * 8,
                          sB[1] + (f * 2 + kc) * 512);
        }
    }
    PIPE_FENCE();          // tile 0 landed

    int cur = 1;
    const int nk = K >> 6;
    for (int kt = 0; kt < nk; ++kt) {
        if (kt + 1 < nk) {
            const int koff = (kt + 1) << 6;
#pragma unroll
            for (int r = 0; r < 2; ++r) {
                const int f = w * 2 + r;
#pragma unroll
                for (int kc = 0; kc < 2; ++kc) {
                    load16_to_lds(A + (size_t)(m0 + f * 16 + l15) * K + koff + kc * 32 + quad * 8,
                                  sA[cur ^ 1] + (f * 2 + kc) * 512);
                    load16_to_lds(Bt + (size_t)(n0 + f * 16 + l15) * K + koff + kc * 32 + quad * 8,
                                  sB[cur ^ 1] + (f * 2 + kc) * 512);
                }
            }
        }
        const u16* bA = sA[cur];
        const u16* bB = sB[cur];
#pragma unroll
        for (int kc = 0; kc < 2; ++kc) {
            bf16x8 af[4], bb[4];
#pragma unroll
            for (int i = 0; i < 4; ++i)
                af[i] = *(const bf16x8*)(bA + ((wr4 + i) * 2 + kc) * 512 + lane * 8);
#pragma unroll
            for (int j = 0; j < 4; ++j)
                bb[j] = *(const bf16x8*)(bB + ((wc4 + j) * 2 + kc) * 512 + lane * 8);
#pragma unroll
            for (int i = 0; i < 4; ++i)
#pragma unroll
                for (int j = 0; j < 4; ++j)
                    acc[i][j] = MFMA16(af[i], bb[j], acc[i][j]);
        }
        if (kt + 1 < nk) {
            PIPE_FENCE();
            cur ^= 1;
        }
    }
#pragma unroll
    for (int i = 0; i < 4; ++i)
#pragma unroll
        for (int j = 0; j < 4; ++j) {
            const int row = m0 + (w >> 1) * 64 + i * 16 + quad * 4;
            const int col = n0 + (w & 1) * 64 + j * 16 + l15;
#pragma unroll
            for (int r = 0; r < 4; ++r)
                store_out(C + (size_t)(row + r) * N + col, acc[i][j][r]);
        }
}

// ---------------------------------------------------- V transpose -> Vt
// R21: rope now fused into gemm1; this is the V-transpose half only.
// grid 512: (64, 2, 4) linearized. Vt [kvh][128][4096] bf16.
__global__ __launch_bounds__(256) void vt_kernel(const u16* __restrict__ QKV,
                                                 u16* __restrict__ Vt) {
    __shared__ u16 tile[64 * 72];
    const int b = blockIdx.x;
    const int k0 = (b & 63) * 64, d0 = ((b >> 6) & 1) * 64, kvh = b >> 7;
    const int t = threadIdx.x;
#pragma unroll
    for (int k = 0; k < 4; ++k) {
        const int u = t + k * 256;
        const int key = u >> 4, dg = u & 15;
        const uint2 v = *(const uint2*)(QKV + (size_t)(k0 + key) * 3072 + 2560 + kvh * 128 + d0 + dg * 4);
        *(uint2*)(tile + key * 72 + dg * 4) = v;
    }
    __syncthreads();
#pragma unroll
    for (int k = 0; k < 4; ++k) {
        const int u = t + k * 256;
        const int d = u >> 4, kg = u & 15;
        union { u16 s[4]; uint2 v; } pk;
#pragma unroll
        for (int i = 0; i < 4; ++i) pk.s[i] = tile[(kg * 4 + i) * 72 + d];
        *(uint2*)(Vt + (size_t)(kvh * 128 + d0 + d) * 4096 + k0 + kg * 4) = pk.v;
    }
}

// ---------------------------------------------------------------- attention partials
// grid 1280 (bid = u*16 + h; 80 units/head, longest-first). Block: 128 q rows x one
// 1024-chunk, KVBLK=64 (R13 optimum). Wave w owns q-cols [w*32,+32): S^T = K*Q^T
// (B=Q in regs, af[2][4]), O^T = V^T*P^T. R9 sync: ping-pong K/V, stage(j+1);
// compute(j); PIPE_FENCE (count-free). Epilogue: part q-major [tile][q][d] fp16.
__device__ __forceinline__ void stage_kv(const u16* __restrict__ QKV,
                                         const u16* __restrict__ Vt,
                                         int kt0, int kvh, int w, int l15, int quad,
                                         u16* bK, u16* bV) {
    const u16* gk = QKV + (size_t)(kt0 + w * 16 + l15) * 3072 + 2048 + kvh * 128 + quad * 8;
#pragma unroll
    for (int kc = 0; kc < 4; ++kc)
        load16_to_lds(gk + kc * 32, bK + (w * 4 + kc) * 512);
#pragma unroll
    for (int r = 0; r < 4; ++r) {
        const int dt = w * 2 + (r >> 1), ks = r & 1;
        load16_to_lds(Vt + (size_t)(kvh * 128 + dt * 16 + l15) * 4096 + kt0 + ks * 32 + quad * 8,
                      bV + (dt * 2 + ks) * 512);
    }
}

__global__ __launch_bounds__(256, 2) void attn_partial(const u16* __restrict__ QKV,
                                                       const u16* __restrict__ Vt,
                                                       u16* __restrict__ part,
                                                       float* __restrict__ ml) {
    __shared__ __align__(16) u16 sK[2][8192];   // ping-pong K frags (buf0 also Q stage w0-1)
    __shared__ __align__(16) u16 sV[2][8192];   // ping-pong V^T frags (buf0 also Q stage w2-3)

    const int t = threadIdx.x;
    const int lane = t & 63, w = t >> 6;
    const int quad = lane >> 4, l15 = lane & 15;
    const int bid = blockIdx.x;
    const int u = bid >> 4, h = bid & 15, kvh = h >> 2;

    // unit decode (longest-first): u<48 full chunks, u>=48 diagonal by desc length
    int qb, c;
    if (u < 8)       { qb = 8 + u; c = 0; }
    else if (u < 24) { const int r = u - 8;  qb = 16 + (r >> 1); c = r & 1; }
    else if (u < 48) { const int r = u - 24; const int q3 = r / 3; qb = 24 + q3; c = r - q3 * 3; }
    else             { const int r = u - 48; const int k = r >> 2; const int g0 = r & 3;
                       qb = g0 * 8 + (7 - k); c = g0; }
    const int g = qb >> 3;
    const int q0 = qb << 7, kv0 = c << 10;
    const int jmax = (c == g) ? (2 * (qb & 7) + 2) : 16;

    // stage Q into buf0 (waves 0-1 -> sK[0], waves 2-3 -> sV[0])
    {
        u16* dst0 = (w < 2) ? sK[0] : sV[0];
        const int fbase = (w & 1) * 8;
#pragma unroll
        for (int idx = 0; idx < 8; ++idx) {
            const int qg = idx >> 2, kc = idx & 3;
            load16_to_lds(QKV + (size_t)(q0 + w * 32 + qg * 16 + l15) * 3072 + h * 128 + kc * 32 + quad * 8,
                          dst0 + (fbase + idx) * 512);
        }
    }
    PIPE_FENCE();          // Q glds drained + barrier: Q visible to all waves
    bf16x8 af[2][4];
    {
        const u16* src0 = (w < 2) ? sK[0] : sV[0];
        const int fbase = (w & 1) * 8;
#pragma unroll
        for (int qg = 0; qg < 2; ++qg)
#pragma unroll
            for (int kc = 0; kc < 4; ++kc)
                af[qg][kc] = *(const bf16x8*)(src0 + (fbase + qg * 4 + kc) * 512 + lane * 8);
    }
    // prefetch tile 0 into buf1 (issued now; drained by the fence below)
    stage_kv(QKV, Vt, kv0, kvh, w, l15, quad, sK[1], sV[1]);
    PIPE_FENCE();          // Q reg-reads drained (lgkm), tile0 landed (vmcnt), barrier

    float m_c[2] = {-1e30f, -1e30f}, l_c[2] = {0.0f, 0.0f};
    f32x4 o_c[8][2] = {};
    const float SCALE = 0.08838834764831845f;            // 128^-0.5
    const float LOG2E = 1.4426950408889634f;
    const float CS = SCALE * LOG2E;                      // fold scale into exp2 fma

    // in-register P^T redistribution constants (loop-invariant)
    const int srcLo = ((quad & 1) << 5) | l15;   // source lane for B-frag elems 0-3
    const int srcHi = srcLo | 16;                // source lane for B-frag elems 4-7
    const bool selB = (quad & 2) != 0;           // j4 = 2ks+1 when target quad >= 2

    int cur = 1;                                 // tile j lives in buf[cur]
    for (int j = 0; j < jmax; ++j) {
        // issue stage of tile j+1 into the other buffer; flies during compute of j
        if (j + 1 < jmax)
            stage_kv(QKV, Vt, kv0 + ((j + 1) << 6), kvh, w, l15, quad,
                     sK[cur ^ 1], sV[cur ^ 1]);

        const u16* bK = sK[cur];
        const u16* bV = sV[cur];
        const int kt0 = kv0 + (j << 6);

        // S^T = K * Q^T : 16 K-frag reads, 32 MFMA (reuse across qg). RAW scores.
        f32x4 sacc[4][2] = {};
#pragma unroll
        for (int j4 = 0; j4 < 4; ++j4)
#pragma unroll
            for (int kc = 0; kc < 4; ++kc) {
                const bf16x8 kf = *(const bf16x8*)(bK + (j4 * 4 + kc) * 512 + lane * 8);
                sacc[j4][0] = MFMA16(kf, af[0][kc], sacc[j4][0]);
                sacc[j4][1] = MFMA16(kf, af[1][kc], sacc[j4][1]);
            }

        // causal mask in raw domain (only last two tiles of diagonal chunk)
        const bool diag = (c == g) && ((j >> 1) == (qb & 7));
        if (diag) {
#pragma unroll
            for (int j4 = 0; j4 < 4; ++j4)
#pragma unroll
                for (int qg = 0; qg < 2; ++qg) {
                    const int qrow = q0 + w * 32 + qg * 16 + l15;
#pragma unroll
                    for (int r = 0; r < 4; ++r) {
                        const int key = kt0 + j4 * 16 + quad * 4 + r;
                        if (key > qrow) sacc[j4][qg][r] = -1e30f;
                    }
                }
        }

        // online softmax + in-register P pack/redistribute, per qg
        bf16x8 pf[2][2];
#pragma unroll
        for (int qg = 0; qg < 2; ++qg) {
            // tree max over 16 raw scores
            f32x4 v01, v23;
#pragma unroll
            for (int r = 0; r < 4; ++r) {
                v01[r] = fmaxf(sacc[0][qg][r], sacc[1][qg][r]);
                v23[r] = fmaxf(sacc[2][qg][r], sacc[3][qg][r]);
            }
            float mx = fmaxf(fmaxf(fmaxf(v01[0], v01[1]), fmaxf(v01[2], v01[3])),
                             fmaxf(fmaxf(v23[0], v23[1]), fmaxf(v23[2], v23[3])));
            mx = fmaxf(mx, __shfl_xor(mx, 16, 64));
            mx = fmaxf(mx, __shfl_xor(mx, 32, 64));
            const float mn = fmaxf(m_c[qg], mx * SCALE);         // scaled domain
            const float alpha = exp2_hw((m_c[qg] - mn) * LOG2E);
            const float kk = -mn * LOG2E;
#pragma unroll
            for (int j4 = 0; j4 < 4; ++j4)
#pragma unroll
                for (int r = 0; r < 4; ++r)
                    sacc[j4][qg][r] = exp2_hw(fmaf(sacc[j4][qg][r], CS, kk));
            const f32x4 pv = (sacc[0][qg] + sacc[1][qg]) + (sacc[2][qg] + sacc[3][qg]);
            float ps = (pv[0] + pv[1]) + (pv[2] + pv[3]);
            ps += __shfl_xor(ps, 16, 64);
            ps += __shfl_xor(ps, 32, 64);
            l_c[qg] = l_c[qg] * alpha + ps;
            m_c[qg] = mn;
#pragma unroll
            for (int dt = 0; dt < 8; ++dt) o_c[dt][qg] *= alpha;

            // pack pe -> bf16 pairs per j4 (source fragment layout)
            u32 pk[4][2];
#pragma unroll
            for (int j4 = 0; j4 < 4; ++j4) {
                pk[j4][0] = pkbf(sacc[j4][qg][0], sacc[j4][qg][1]);
                pk[j4][1] = pkbf(sacc[j4][qg][2], sacc[j4][qg][3]);
            }
            // redistribute to PV B-frag: lane(quad,q) needs keys ks*32+quad*8+e
            // from source lanes (quad&1)*32+l15 (+16), j4 = 2ks + (quad>>1).
#pragma unroll
            for (int ks = 0; ks < 2; ++ks) {
                union { u32 wd[4]; bf16x8 v; } bu;
                const u32 a0 = pk[2 * ks][0], a1 = pk[2 * ks][1];
                const u32 b0 = pk[2 * ks + 1][0], b1 = pk[2 * ks + 1][1];
                const u32 xa0 = (u32)__shfl((int)a0, srcLo, 64);
                const u32 xb0 = (u32)__shfl((int)b0, srcLo, 64);
                bu.wd[0] = selB ? xb0 : xa0;
                const u32 xa1 = (u32)__shfl((int)a1, srcLo, 64);
                const u32 xb1 = (u32)__shfl((int)b1, srcLo, 64);
                bu.wd[1] = selB ? xb1 : xa1;
                const u32 ya0 = (u32)__shfl((int)a0, srcHi, 64);
                const u32 yb0 = (u32)__shfl((int)b0, srcHi, 64);
                bu.wd[2] = selB ? yb0 : ya0;
                const u32 ya1 = (u32)__shfl((int)a1, srcHi, 64);
                const u32 yb1 = (u32)__shfl((int)b1, srcHi, 64);
                bu.wd[3] = selB ? yb1 : ya1;
                pf[qg][ks] = bu.v;
            }
        }

        // O^T += V^T * P^T : 16 V-frag reads, 32 MFMA (reuse across qg)
#pragma unroll
        for (int ks = 0; ks < 2; ++ks) {
#pragma unroll
            for (int dt = 0; dt < 8; ++dt) {
                const bf16x8 vf = *(const bf16x8*)(bV + (dt * 2 + ks) * 512 + lane * 8);
                o_c[dt][0] = MFMA16(vf, pf[0][ks], o_c[dt][0]);
                o_c[dt][1] = MFMA16(vf, pf[1][ks], o_c[dt][1]);
            }
        }

        // end-of-tile fence: tile j+1 glds landed; all waves done reading buf[cur]
        if (j + 1 < jmax) {
            PIPE_FENCE();
            cur ^= 1;
        }
    }

    // epilogue: part q-major [bid][q=128][d=128] fp16 (8B vector stores),
    // ml [bid][q=128][2] fp32
#pragma unroll
    for (int qg = 0; qg < 2; ++qg) {
        const float invl = 1.0f / l_c[qg];
        const int q = w * 32 + qg * 16 + l15;
        u16* pbase = part + (size_t)bid * 16384 + (size_t)q * 128 + quad * 4;
#pragma unroll
        for (int dt = 0; dt < 8; ++dt) {
            union { u16 s[4]; uint2 v; } pk4;
#pragma unroll
            for (int r = 0; r < 4; ++r) pk4.s[r] = f2h(o_c[dt][qg][r] * invl);
            *(uint2*)(pbase + dt * 16) = pk4.v;
        }
        if (quad == 0) {
            ml[(size_t)bid * 256 + q * 2] = m_c[qg];
            ml[(size_t)bid * 256 + q * 2 + 1] = l_c[qg];
        }
    }
}

// ---------------------------------------------------------------- merge partials
// grid (512, 8): x = qb*16+h, y = qrow-group. Thread: slot = t&15 owns
// d [slot*8, +8) (one uint4 = 8 fp16), qrow = y*16 + (t>>4). 16 consecutive
// lanes read 256B contiguous per qrow -> fully coalesced, 8x fewer instrs.
// Reference merge IN CHUNK ORDER: d = a + sE + 1e-10; o = o*(l_g/d) + ohat*sE/d.
__global__ __launch_bounds__(256) void attn_merge(const u16* __restrict__ part,
                                                  const float* __restrict__ ml,
                                                  u16* __restrict__ attn) {
    const int b = blockIdx.x;
    const int qb = b >> 4, h = b & 15;
    const int g = qb >> 3;
    const int t = threadIdx.x;
    const int slot = t & 15;
    const int qrow = blockIdx.y * 16 + (t >> 4);
    const int d0 = slot * 8;

    float o[8];
#pragma unroll
    for (int i = 0; i < 8; ++i) o[i] = 0.0f;
    float m_g = -1e30f, l_g = 0.0f;

    for (int c = 0; c <= g; ++c) {
        int u;
        if (c == g)      u = 48 + (7 - (qb & 7)) * 4 + g;
        else if (g == 1) u = qb - 8;
        else if (g == 2) u = 8 + (qb - 16) * 2 + c;
        else             u = 24 + (qb - 24) * 3 + c;
        const int tile = u * 16 + h;
        const float m_c = ml[(size_t)tile * 256 + qrow * 2];
        const float l_c = ml[(size_t)tile * 256 + qrow * 2 + 1];
        const float mn = fmaxf(m_g, m_c);
        const float a = l_g * __expf(m_g - mn);
        const float eC = __expf(m_c - mn);
        const float sE = l_c * eC;
        const float d = a + sE + 1e-10f;
        const float f_old = l_g / d;
        const float f_new = sE / d;
        union { u16 s[8]; uint4 v; } ld;
        ld.v = *(const uint4*)(part + (size_t)tile * 16384 + (size_t)qrow * 128 + d0);
#pragma unroll
        for (int jj = 0; jj < 8; ++jj)
            o[jj] = o[jj] * f_old + h2f(ld.s[jj]) * f_new;
        l_g = a + sE;
        m_g = mn;
    }

    union { u16 s[8]; uint4 v; } pk;
#pragma unroll
    for (int i = 0; i < 8; ++i) pk.s[i] = f2bf(o[i]);
    *(uint4*)(attn + (size_t)(qb * 128 + qrow) * 2048 + h * 128 + d0) = pk.v;
}

// ---------------------------------------------------------------- launch
extern "C" void kernel_launch(void* const* d_in, const int* in_sizes, int n_in,
                              void* d_out, int out_size, void* d_ws, size_t ws_size,
                              hipStream_t stream) {
    const float* X  = (const float*)d_in[0];
    const int* pos  = (const int*)d_in[1];
    const float* Wq = (const float*)d_in[2];
    const float* Wk = (const float*)d_in[3];
    const float* Wv = (const float*)d_in[4];
    const float* Wo = (const float*)d_in[5];
    float* out = (float*)d_out;
    char* ws = (char*)d_ws;

    u16*   part = (u16*)(ws);
    u16*   Xbf  = (u16*)(ws);                      // overlay (dead before part)
    u16*   Wt   = (u16*)(ws + 16777216);           // [3072][2048] overlay
    u16*   QKV  = (u16*)(ws + 41943040);
    u16*   attn = (u16*)(ws + 41943040);           // overlay QKV (dead after partials)
    u16*   Vt   = (u16*)(ws + 67108864);
    float* ml   = (float*)(ws + 71303168);
    u16*   Wot  = (u16*)(ws + 72613888);

    convert_f32_bf16<<<2048, 256, 0, stream>>>(X, Xbf);
    transpose_w4<<<dim3(80, 32), 256, 0, stream>>>(Wq, Wk, Wv, Wo, Wt, Wot);

    gemm_qkv<<<dim3(32, 24), 256, 0, stream>>>(Xbf, Wt, QKV, pos, 4096, 3072, 2048);

    vt_kernel<<<512, 256, 0, stream>>>(QKV, Vt);

    attn_partial<<<1280, 256, 0, stream>>>(QKV, Vt, part, ml);
    attn_merge<<<dim3(512, 8), 256, 0, stream>>>(part, ml, attn);

    gemm_bt64<float><<<dim3(32, 16), 256, 0, stream>>>(attn, Wot, out, 4096, 2048, 2048);
}

// Round 16
// 416.139 us; speedup vs baseline: 1.0551x; 1.0551x over previous
//
#include <hip/hip_runtime.h>
#include <cstdint>
#include <cstddef>

// B=1, S=4096, HIDDEN=2048, HEADS=16, KVH=4, HD=128, CHUNK=1024.
// R22: REVERT to R20 (416.1us, session equal-best). R21's rope-into-gemm1
// fusion regressed (439): the 5.2M cos/sin pairs moved from a high-occupancy
// memory-bound kernel (trig hidden under HBM latency) into gemm1's fence-
// synchronized epilogue tail at 3 blk/CU — relocated VALU to the critical
// path. Fusion only wins when fused work hides under existing stalls.
// Final config: BK=32-dbuf gemm1 (R19 +10us), BK=64-dbuf gemm2 (R20),
// R13-optimum attn (KVBLK=64, count-free fence pipeline), q-major part
// epilogue (R15/16), coalesced-vector merge (R16), vectorized fast-math
// rope (R13/R18). Session: 448 -> 416 (-7.2%).
// Measured-and-rejected: T13 defer-rescale (raced), counted-vmcnt mid-fence
// (raced), setprio (null/neg), attn KVBLK=32 (+5us), prep fusion (noise),
// rope-into-gemm fusion (-23us).
//
// ws arena (bytes), liveness overlays:
//   part  @ 0          41,943,040   (overlays Xbf@0 16MB + Wt@16MB 12.6MB)
//   QKV   @ 41,943,040 25,165,824   ([4096][3072]: Q | K | V bf16)
//     attn @ 41,943,040 16,777,216  (overlay after partials done)
//   Vt    @ 67,108,864  4,194,304   ([kvh][128][4096] bf16)
//   ml    @ 71,303,168  1,310,720   (fp32 m,l per q-row per partial)
//   Wot   @ 72,613,888  8,388,608
//   total 81,002,496 (~77.3 MB)

typedef unsigned short u16;
typedef unsigned int u32;
typedef float f32x4 __attribute__((ext_vector_type(4)));
typedef __bf16 bf16x8 __attribute__((ext_vector_type(8)));

__device__ __forceinline__ u16 f2bf(float f) {
    union { float f; u32 u; } v; v.f = f;
    u32 u = v.u;
    u += 0x7fffu + ((u >> 16) & 1u);
    return (u16)(u >> 16);
}
__device__ __forceinline__ float bf2f(u16 b) {
    union { u32 u; float f; } v; v.u = ((u32)b) << 16;
    return v.f;
}
__device__ __forceinline__ u16 f2h(float f) {
    union { _Float16 h; u16 u; } v; v.h = (_Float16)f; return v.u;
}
__device__ __forceinline__ float h2f(u16 u) {
    union { u16 u; _Float16 h; } v; v.u = u; return (float)v.h;
}
// packed bf16 pair via native casts (compiler emits v_cvt_pk_bf16_f32, RNE)
__device__ __forceinline__ u32 pkbf(float lo, float hi) {
    union { __bf16 h[2]; u32 u; } v;
    v.h[0] = (__bf16)lo; v.h[1] = (__bf16)hi;
    return v.u;
}
// v_exp_f32 computes 2^x (single HW instruction; ISA §3)
__device__ __forceinline__ float exp2_hw(float x) {
    float r;
    asm("v_exp_f32 %0, %1" : "=v"(r) : "v"(x));
    return r;
}

__device__ __forceinline__ void load16_to_lds(const void* g, void* l) {
    __builtin_amdgcn_global_load_lds((const __attribute__((address_space(1))) u32*)g,
                                     (__attribute__((address_space(3))) u32*)l,
                                     16, 0, 0);
}

// Explicit pipeline fence: drain this wave's vmem (glds) + lds ops, then
// block barrier. sched_barrier(0) on both sides: nothing moves across.
#define PIPE_FENCE() do {                                        \
    __builtin_amdgcn_sched_barrier(0);                           \
    asm volatile("s_waitcnt vmcnt(0) lgkmcnt(0)" ::: "memory");  \
    __builtin_amdgcn_sched_barrier(0);                           \
    __builtin_amdgcn_s_barrier();                                \
    __builtin_amdgcn_sched_barrier(0);                           \
} while (0)

#define MFMA16(a, b, c) __builtin_amdgcn_mfma_f32_16x16x32_bf16((a), (b), (c), 0, 0, 0)

// ---------------------------------------------------------------- convert X
__global__ __launch_bounds__(256) void convert_f32_bf16(const float* __restrict__ X,
                                                        u16* __restrict__ Y) {
    const int base = (blockIdx.x * 1024 + threadIdx.x) * 4;
#pragma unroll
    for (int k = 0; k < 4; ++k) {
        const int i = base + k * 1024;
        const float4 v = *(const float4*)(X + i);
        union { u16 s[4]; uint2 u; } pk;
        pk.s[0] = f2bf(v.x); pk.s[1] = f2bf(v.y); pk.s[2] = f2bf(v.z); pk.s[3] = f2bf(v.w);
        *(uint2*)(Y + i) = pk.u;
    }
}

// -------------------------- fused transpose of all 4 weights -> bf16 [N][K]
// grid (80, 32): x<32 Wq->Wt, x<40 Wk->Wt+2048*2048, x<48 Wv->Wt+2560*2048,
// x>=48 Wo->Wot. Source is [K=2048][N] fp32.
__global__ __launch_bounds__(256) void transpose_w4(const float* __restrict__ Wq,
                                                    const float* __restrict__ Wk,
                                                    const float* __restrict__ Wv,
                                                    const float* __restrict__ Wo,
                                                    u16* __restrict__ Wt,
                                                    u16* __restrict__ Wot) {
    __shared__ float tile[64][65];
    const int bx = blockIdx.x;
    const float* W; u16* dst; int N, n0;
    if (bx < 32)      { W = Wq; dst = Wt;                          N = 2048; n0 = bx * 64; }
    else if (bx < 40) { W = Wk; dst = Wt + (size_t)2048 * 2048;    N = 512;  n0 = (bx - 32) * 64; }
    else if (bx < 48) { W = Wv; dst = Wt + (size_t)2560 * 2048;    N = 512;  n0 = (bx - 40) * 64; }
    else              { W = Wo; dst = Wot;                         N = 2048; n0 = (bx - 48) * 64; }
    const int k0 = blockIdx.y * 64;
    const int tc = threadIdx.x & 63, tr = threadIdx.x >> 6;
#pragma unroll
    for (int i = 0; i < 64; i += 4)
        tile[tc][tr + i] = W[(size_t)(k0 + tr + i) * N + n0 + tc];
    __syncthreads();
#pragma unroll
    for (int i = 0; i < 64; i += 4)
        dst[(size_t)(n0 + tr + i) * 2048 + k0 + tc] = f2bf(tile[tr + i][tc]);
}

// ---------------------------------------------------------------- GEMM C = A * Bt^T
__device__ __forceinline__ void store_out(float* p, float v) { *p = v; }
__device__ __forceinline__ void store_out(u16* p, float v) { *p = f2bf(v); }

// R19 variant: BK=32, double-buffered (2x8KB per matrix = 32KB LDS), prefetch
// stage(k+1); compute(k); ONE count-free PIPE_FENCE per K-step. (gemm1: 3 blk/CU)
template <typename OutT>
__global__ __launch_bounds__(256) void gemm_bt(const u16* __restrict__ A,
                                               const u16* __restrict__ Bt,
                                               OutT* __restrict__ C,
                                               int M, int N, int K) {
    __shared__ __align__(16) u16 sA[2][4096];   // 8KB each: 8 A-frags (16x32)
    __shared__ __align__(16) u16 sB[2][4096];   // 8KB each: 8 B-frags (16x32)
    const int t = threadIdx.x;
    const int lane = t & 63, w = t >> 6;
    const int quad = lane >> 4, l15 = lane & 15;
    const int m0 = blockIdx.x << 7, n0 = blockIdx.y << 7;
    const int wr4 = (w >> 1) * 4, wc4 = (w & 1) * 4;
    f32x4 acc[4][4] = {};

    // prologue: stage K-tile 0 into buf[1]
#pragma unroll
    for (int r = 0; r < 2; ++r) {
        const int f = w * 2 + r;
        load16_to_lds(A + (size_t)(m0 + f * 16 + l15) * K + quad * 8, sA[1] + f * 512);
        load16_to_lds(Bt + (size_t)(n0 + f * 16 + l15) * K + quad * 8, sB[1] + f * 512);
    }
    PIPE_FENCE();          // tile 0 landed, visible to all waves

    int cur = 1;
    const int nk = K >> 5;
    for (int kt = 0; kt < nk; ++kt) {
        if (kt + 1 < nk) {
            const int koff = (kt + 1) << 5;
#pragma unroll
            for (int r = 0; r < 2; ++r) {
                const int f = w * 2 + r;
                load16_to_lds(A + (size_t)(m0 + f * 16 + l15) * K + koff + quad * 8,
                              sA[cur ^ 1] + f * 512);
                load16_to_lds(Bt + (size_t)(n0 + f * 16 + l15) * K + koff + quad * 8,
                              sB[cur ^ 1] + f * 512);
            }
        }
        const u16* bA = sA[cur];
        const u16* bB = sB[cur];
        bf16x8 af[4], bb[4];
#pragma unroll
        for (int i = 0; i < 4; ++i)
            af[i] = *(const bf16x8*)(bA + (wr4 + i) * 512 + lane * 8);
#pragma unroll
        for (int j = 0; j < 4; ++j)
            bb[j] = *(const bf16x8*)(bB + (wc4 + j) * 512 + lane * 8);
#pragma unroll
        for (int i = 0; i < 4; ++i)
#pragma unroll
            for (int j = 0; j < 4; ++j)
                acc[i][j] = MFMA16(af[i], bb[j], acc[i][j]);
        if (kt + 1 < nk) {
            PIPE_FENCE();
            cur ^= 1;
        }
    }
#pragma unroll
    for (int i = 0; i < 4; ++i)
#pragma unroll
        for (int j = 0; j < 4; ++j) {
            const int row = m0 + (w >> 1) * 64 + i * 16 + quad * 4;
            const int col = n0 + (w & 1) * 64 + j * 16 + l15;
#pragma unroll
            for (int r = 0; r < 4; ++r)
                store_out(C + (size_t)(row + r) * N + col, acc[i][j][r]);
        }
}

// R20 variant: BK=64, double-buffered (2x16KB per matrix = 64KB LDS -> 2 blk/CU),
// same prefetch + count-free fence. 32 MFMA + 16 ds_read per K-step: compute
// phase (~500cy) covers glds flight; half the fences of BK=32. For gemm2 whose
// grid (512 blocks) is exactly 2/CU — zero occupancy loss.
template <typename OutT>
__global__ __launch_bounds__(256, 2) void gemm_bt64(const u16* __restrict__ A,
                                                    const u16* __restrict__ Bt,
                                                    OutT* __restrict__ C,
                                                    int M, int N, int K) {
    __shared__ __align__(16) u16 sA[2][8192];   // 16KB each: 16 A-frags (16x32)
    __shared__ __align__(16) u16 sB[2][8192];
    const int t = threadIdx.x;
    const int lane = t & 63, w = t >> 6;
    const int quad = lane >> 4, l15 = lane & 15;
    const int m0 = blockIdx.x << 7, n0 = blockIdx.y << 7;
    const int wr4 = (w >> 1) * 4, wc4 = (w & 1) * 4;
    f32x4 acc[4][4] = {};

    // prologue: stage K-tile 0 (64 wide) into buf[1]
#pragma unroll
    for (int r = 0; r < 2; ++r) {
        const int f = w * 2 + r;
#pragma unroll
        for (int kc = 0; kc < 2; ++kc) {
            load16_to_lds(A + (size_t)(m0 + f * 16 + l15) * K + kc * 32 + quad * 8,
                          sA[1] + (f * 2 + kc) * 512);
            load16_to_lds(Bt + (size_t)(n0 + f * 16 + l15) * K + kc * 32 + quad * 8,
                          sB[1] + (f * 2 + kc) * 512);
        }
    }
    PIPE_FENCE();          // tile 0 landed

    int cur = 1;
    const int nk = K >> 6;
    for (int kt = 0; kt < nk; ++kt) {
        if (kt + 1 < nk) {
            const int koff = (kt + 1) << 6;
#pragma unroll
            for (int r = 0; r < 2; ++r) {
                const int f = w * 2 + r;
#pragma unroll
                for (int kc = 0; kc < 2; ++kc) {
                    load16_to_lds(A + (size_t)(m0 + f * 16 + l15) * K + koff + kc * 32 + quad * 8,
                                  sA[cur ^ 1] + (f * 2 + kc) * 512);
                    load16_to_lds(Bt + (size_t)(n0 + f * 16 + l15) * K + koff + kc * 32 + quad * 8,
                                  sB[cur ^ 1] + (f * 2 + kc) * 512);
                }
            }
        }
        const u16* bA = sA[cur];
        const u16* bB = sB[cur];
#pragma unroll
        for (int kc = 0; kc < 2; ++kc) {
            bf16x8 af[4], bb[4];
#pragma unroll
            for (int i = 0; i < 4; ++i)
                af[i] = *(const bf16x8*)(bA + ((wr4 + i) * 2 + kc) * 512 + lane * 8);
#pragma unroll
            for (int j = 0; j < 4; ++j)
                bb[j] = *(const bf16x8*)(bB + ((wc4 + j) * 2 + kc) * 512 + lane * 8);
#pragma unroll
            for (int i = 0; i < 4; ++i)
#pragma unroll
                for (int j = 0; j < 4; ++j)
                    acc[i][j] = MFMA16(af[i], bb[j], acc[i][j]);
        }
        if (kt + 1 < nk) {
            PIPE_FENCE();
            cur ^= 1;
        }
    }
#pragma unroll
    for (int i = 0; i < 4; ++i)
#pragma unroll
        for (int j = 0; j < 4; ++j) {
            const int row = m0 + (w >> 1) * 64 + i * 16 + quad * 4;
            const int col = n0 + (w & 1) * 64 + j * 16 + l15;
#pragma unroll
            for (int r = 0; r < 4; ++r)
                store_out(C + (size_t)(row + r) * N + col, acc[i][j][r]);
        }
}

// --------------------------------------- fused YaRN RoPE (in place) + V transpose
// R18: vectorized rope — each thread handles 4 rotation pairs (uint2 at
// i..i+3 and i+64..i+67). blocks 0..5119: rope on QKV. blocks 5120..5631:
// transpose V (cols 2560+) -> Vt. Fast-math trig (R13).
__global__ __launch_bounds__(256) void rope_vt_kernel(u16* __restrict__ QKV,
                                                      u16* __restrict__ Vt,
                                                      const int* __restrict__ pos_ids) {
    __shared__ u16 tile[64 * 72];
    if (blockIdx.x >= 5120) {
        const int b = blockIdx.x - 5120;            // (64, 2, 4) linearized
        const int k0 = (b & 63) * 64, d0 = ((b >> 6) & 1) * 64, kvh = b >> 7;
        const int t = threadIdx.x;
#pragma unroll
        for (int k = 0; k < 4; ++k) {
            const int u = t + k * 256;
            const int key = u >> 4, dg = u & 15;
            const uint2 v = *(const uint2*)(QKV + (size_t)(k0 + key) * 3072 + 2560 + kvh * 128 + d0 + dg * 4);
            *(uint2*)(tile + key * 72 + dg * 4) = v;
        }
        __syncthreads();
#pragma unroll
        for (int k = 0; k < 4; ++k) {
            const int u = t + k * 256;
            const int d = u >> 4, kg = u & 15;
            union { u16 s[4]; uint2 v; } pk;
#pragma unroll
            for (int i = 0; i < 4; ++i) pk.s[i] = tile[(kg * 4 + i) * 72 + d];
            *(uint2*)(Vt + (size_t)(kvh * 128 + d0 + d) * 4096 + k0 + kg * 4) = pk.v;
        }
        return;
    }
    const int u = blockIdx.x * 256 + threadIdx.x;
    const int NQ4 = 4096 * 16 * 16;                 // Q rope threads (4 pairs each)
    u16* p;
    int s, i4;
    if (u < NQ4) {
        s = u >> 8;
        const int rest = u & 255;
        const int h = rest >> 4;
        i4 = rest & 15;
        p = QKV + (size_t)s * 3072 + h * 128 + i4 * 4;
    } else {
        const int u2 = u - NQ4;
        s = u2 >> 6;
        const int rest = u2 & 63;
        const int h = rest >> 4;
        i4 = rest & 15;
        p = QKV + (size_t)s * 3072 + 2048 + h * 128 + i4 * 4;
    }
    const float pf = (float)pos_ids[s];
    const float MS = 1.2772588722239781f;
    union { u16 s4[4]; uint2 v; } lo, hi, so, sh;
    lo.v = *(const uint2*)(p);                      // x1: i..i+3
    hi.v = *(const uint2*)(p + 64);                 // x2: i+64..i+67
#pragma unroll
    for (int e = 0; e < 4; ++e) {
        const float fi = (float)(i4 * 4 + e);
        // 500000^(-fi/64) = exp2(-fi*log2(500000)/64); log2(5e5)/64 = 0.29580637
        const float inv_ex = exp2_hw(fi * -0.29580637f);
        const float inv_in = inv_ex * (1.0f / 16.0f);
        const float sm = fminf(fmaxf((fi - 18.0f) * (1.0f / 17.0f), 0.0f), 1.0f);
        const float inv = (1.0f - sm) * inv_in + sm * inv_ex;
        const float ph = pf * inv;                  // <= ~256 rad (~41 rev)
        const float cs = __cosf(ph) * MS, sn = __sinf(ph) * MS;
        const float x1 = bf2f(lo.s4[e]), x2 = bf2f(hi.s4[e]);
        so.s4[e] = f2bf(x1 * cs - x2 * sn);
        sh.s4[e] = f2bf(x2 * cs + x1 * sn);
    }
    *(uint2*)(p) = so.v;
    *(uint2*)(p + 64) = sh.v;
}

// ---------------------------------------------------------------- attention partials
// grid 1280 (bid = u*16 + h; 80 units/head, longest-first). Block: 128 q rows x one
// 1024-chunk, KVBLK=64 (R13 optimum). Wave w owns q-cols [w*32,+32): S^T = K*Q^T
// (B=Q in regs, af[2][4]), O^T = V^T*P^T. R9 sync: ping-pong K/V, stage(j+1);
// compute(j); PIPE_FENCE (count-free). Epilogue: part q-major [tile][q][d] fp16.
__device__ __forceinline__ void stage_kv(const u16* __restrict__ QKV,
                                         const u16* __restrict__ Vt,
                                         int kt0, int kvh, int w, int l15, int quad,
                                         u16* bK, u16* bV) {
    const u16* gk = QKV + (size_t)(kt0 + w * 16 + l15) * 3072 + 2048 + kvh * 128 + quad * 8;
#pragma unroll
    for (int kc = 0; kc < 4; ++kc)
        load16_to_lds(gk + kc * 32, bK + (w * 4 + kc) * 512);
#pragma unroll
    for (int r = 0; r < 4; ++r) {
        const int dt = w * 2 + (r >> 1), ks = r & 1;
        load16_to_lds(Vt + (size_t)(kvh * 128 + dt * 16 + l15) * 4096 + kt0 + ks * 32 + quad * 8,
                      bV + (dt * 2 + ks) * 512);
    }
}

__global__ __launch_bounds__(256, 2) void attn_partial(const u16* __restrict__ QKV,
                                                       const u16* __restrict__ Vt,
                                                       u16* __restrict__ part,
                                                       float* __restrict__ ml) {
    __shared__ __align__(16) u16 sK[2][8192];   // ping-pong K frags (buf0 also Q stage w0-1)
    __shared__ __align__(16) u16 sV[2][8192];   // ping-pong V^T frags (buf0 also Q stage w2-3)

    const int t = threadIdx.x;
    const int lane = t & 63, w = t >> 6;
    const int quad = lane >> 4, l15 = lane & 15;
    const int bid = blockIdx.x;
    const int u = bid >> 4, h = bid & 15, kvh = h >> 2;

    // unit decode (longest-first): u<48 full chunks, u>=48 diagonal by desc length
    int qb, c;
    if (u < 8)       { qb = 8 + u; c = 0; }
    else if (u < 24) { const int r = u - 8;  qb = 16 + (r >> 1); c = r & 1; }
    else if (u < 48) { const int r = u - 24; const int q3 = r / 3; qb = 24 + q3; c = r - q3 * 3; }
    else             { const int r = u - 48; const int k = r >> 2; const int g0 = r & 3;
                       qb = g0 * 8 + (7 - k); c = g0; }
    const int g = qb >> 3;
    const int q0 = qb << 7, kv0 = c << 10;
    const int jmax = (c == g) ? (2 * (qb & 7) + 2) : 16;

    // stage Q into buf0 (waves 0-1 -> sK[0], waves 2-3 -> sV[0])
    {
        u16* dst0 = (w < 2) ? sK[0] : sV[0];
        const int fbase = (w & 1) * 8;
#pragma unroll
        for (int idx = 0; idx < 8; ++idx) {
            const int qg = idx >> 2, kc = idx & 3;
            load16_to_lds(QKV + (size_t)(q0 + w * 32 + qg * 16 + l15) * 3072 + h * 128 + kc * 32 + quad * 8,
                          dst0 + (fbase + idx) * 512);
        }
    }
    PIPE_FENCE();          // Q glds drained + barrier: Q visible to all waves
    bf16x8 af[2][4];
    {
        const u16* src0 = (w < 2) ? sK[0] : sV[0];
        const int fbase = (w & 1) * 8;
#pragma unroll
        for (int qg = 0; qg < 2; ++qg)
#pragma unroll
            for (int kc = 0; kc < 4; ++kc)
                af[qg][kc] = *(const bf16x8*)(src0 + (fbase + qg * 4 + kc) * 512 + lane * 8);
    }
    // prefetch tile 0 into buf1 (issued now; drained by the fence below)
    stage_kv(QKV, Vt, kv0, kvh, w, l15, quad, sK[1], sV[1]);
    PIPE_FENCE();          // Q reg-reads drained (lgkm), tile0 landed (vmcnt), barrier

    float m_c[2] = {-1e30f, -1e30f}, l_c[2] = {0.0f, 0.0f};
    f32x4 o_c[8][2] = {};
    const float SCALE = 0.08838834764831845f;            // 128^-0.5
    const float LOG2E = 1.4426950408889634f;
    const float CS = SCALE * LOG2E;                      // fold scale into exp2 fma

    // in-register P^T redistribution constants (loop-invariant)
    const int srcLo = ((quad & 1) << 5) | l15;   // source lane for B-frag elems 0-3
    const int srcHi = srcLo | 16;                // source lane for B-frag elems 4-7
    const bool selB = (quad & 2) != 0;           // j4 = 2ks+1 when target quad >= 2

    int cur = 1;                                 // tile j lives in buf[cur]
    for (int j = 0; j < jmax; ++j) {
        // issue stage of tile j+1 into the other buffer; flies during compute of j
        if (j + 1 < jmax)
            stage_kv(QKV, Vt, kv0 + ((j + 1) << 6), kvh, w, l15, quad,
                     sK[cur ^ 1], sV[cur ^ 1]);

        const u16* bK = sK[cur];
        const u16* bV = sV[cur];
        const int kt0 = kv0 + (j << 6);

        // S^T = K * Q^T : 16 K-frag reads, 32 MFMA (reuse across qg). RAW scores.
        f32x4 sacc[4][2] = {};
#pragma unroll
        for (int j4 = 0; j4 < 4; ++j4)
#pragma unroll
            for (int kc = 0; kc < 4; ++kc) {
                const bf16x8 kf = *(const bf16x8*)(bK + (j4 * 4 + kc) * 512 + lane * 8);
                sacc[j4][0] = MFMA16(kf, af[0][kc], sacc[j4][0]);
                sacc[j4][1] = MFMA16(kf, af[1][kc], sacc[j4][1]);
            }

        // causal mask in raw domain (only last two tiles of diagonal chunk)
        const bool diag = (c == g) && ((j >> 1) == (qb & 7));
        if (diag) {
#pragma unroll
            for (int j4 = 0; j4 < 4; ++j4)
#pragma unroll
                for (int qg = 0; qg < 2; ++qg) {
                    const int qrow = q0 + w * 32 + qg * 16 + l15;
#pragma unroll
                    for (int r = 0; r < 4; ++r) {
                        const int key = kt0 + j4 * 16 + quad * 4 + r;
                        if (key > qrow) sacc[j4][qg][r] = -1e30f;
                    }
                }
        }

        // online softmax + in-register P pack/redistribute, per qg
        bf16x8 pf[2][2];
#pragma unroll
        for (int qg = 0; qg < 2; ++qg) {
            // tree max over 16 raw scores
            f32x4 v01, v23;
#pragma unroll
            for (int r = 0; r < 4; ++r) {
                v01[r] = fmaxf(sacc[0][qg][r], sacc[1][qg][r]);
                v23[r] = fmaxf(sacc[2][qg][r], sacc[3][qg][r]);
            }
            float mx = fmaxf(fmaxf(fmaxf(v01[0], v01[1]), fmaxf(v01[2], v01[3])),
                             fmaxf(fmaxf(v23[0], v23[1]), fmaxf(v23[2], v23[3])));
            mx = fmaxf(mx, __shfl_xor(mx, 16, 64));
            mx = fmaxf(mx, __shfl_xor(mx, 32, 64));
            const float mn = fmaxf(m_c[qg], mx * SCALE);         // scaled domain
            const float alpha = exp2_hw((m_c[qg] - mn) * LOG2E);
            const float kk = -mn * LOG2E;
#pragma unroll
            for (int j4 = 0; j4 < 4; ++j4)
#pragma unroll
                for (int r = 0; r < 4; ++r)
                    sacc[j4][qg][r] = exp2_hw(fmaf(sacc[j4][qg][r], CS, kk));
            const f32x4 pv = (sacc[0][qg] + sacc[1][qg]) + (sacc[2][qg] + sacc[3][qg]);
            float ps = (pv[0] + pv[1]) + (pv[2] + pv[3]);
            ps += __shfl_xor(ps, 16, 64);
            ps += __shfl_xor(ps, 32, 64);
            l_c[qg] = l_c[qg] * alpha + ps;
            m_c[qg] = mn;
#pragma unroll
            for (int dt = 0; dt < 8; ++dt) o_c[dt][qg] *= alpha;

            // pack pe -> bf16 pairs per j4 (source fragment layout)
            u32 pk[4][2];
#pragma unroll
            for (int j4 = 0; j4 < 4; ++j4) {
                pk[j4][0] = pkbf(sacc[j4][qg][0], sacc[j4][qg][1]);
                pk[j4][1] = pkbf(sacc[j4][qg][2], sacc[j4][qg][3]);
            }
            // redistribute to PV B-frag: lane(quad,q) needs keys ks*32+quad*8+e
            // from source lanes (quad&1)*32+l15 (+16), j4 = 2ks + (quad>>1).
#pragma unroll
            for (int ks = 0; ks < 2; ++ks) {
                union { u32 wd[4]; bf16x8 v; } bu;
                const u32 a0 = pk[2 * ks][0], a1 = pk[2 * ks][1];
                const u32 b0 = pk[2 * ks + 1][0], b1 = pk[2 * ks + 1][1];
                const u32 xa0 = (u32)__shfl((int)a0, srcLo, 64);
                const u32 xb0 = (u32)__shfl((int)b0, srcLo, 64);
                bu.wd[0] = selB ? xb0 : xa0;
                const u32 xa1 = (u32)__shfl((int)a1, srcLo, 64);
                const u32 xb1 = (u32)__shfl((int)b1, srcLo, 64);
                bu.wd[1] = selB ? xb1 : xa1;
                const u32 ya0 = (u32)__shfl((int)a0, srcHi, 64);
                const u32 yb0 = (u32)__shfl((int)b0, srcHi, 64);
                bu.wd[2] = selB ? yb0 : ya0;
                const u32 ya1 = (u32)__shfl((int)a1, srcHi, 64);
                const u32 yb1 = (u32)__shfl((int)b1, srcHi, 64);
                bu.wd[3] = selB ? yb1 : ya1;
                pf[qg][ks] = bu.v;
            }
        }

        // O^T += V^T * P^T : 16 V-frag reads, 32 MFMA (reuse across qg)
#pragma unroll
        for (int ks = 0; ks < 2; ++ks) {
#pragma unroll
            for (int dt = 0; dt < 8; ++dt) {
                const bf16x8 vf = *(const bf16x8*)(bV + (dt * 2 + ks) * 512 + lane * 8);
                o_c[dt][0] = MFMA16(vf, pf[0][ks], o_c[dt][0]);
                o_c[dt][1] = MFMA16(vf, pf[1][ks], o_c[dt][1]);
            }
        }

        // end-of-tile fence: tile j+1 glds landed; all waves done reading buf[cur]
        if (j + 1 < jmax) {
            PIPE_FENCE();
            cur ^= 1;
        }
    }

    // epilogue: part q-major [bid][q=128][d=128] fp16 (8B vector stores),
    // ml [bid][q=128][2] fp32
#pragma unroll
    for (int qg = 0; qg < 2; ++qg) {
        const float invl = 1.0f / l_c[qg];
        const int q = w * 32 + qg * 16 + l15;
        u16* pbase = part + (size_t)bid * 16384 + (size_t)q * 128 + quad * 4;
#pragma unroll
        for (int dt = 0; dt < 8; ++dt) {
            union { u16 s[4]; uint2 v; } pk4;
#pragma unroll
            for (int r = 0; r < 4; ++r) pk4.s[r] = f2h(o_c[dt][qg][r] * invl);
            *(uint2*)(pbase + dt * 16) = pk4.v;
        }
        if (quad == 0) {
            ml[(size_t)bid * 256 + q * 2] = m_c[qg];
            ml[(size_t)bid * 256 + q * 2 + 1] = l_c[qg];
        }
    }
}

// ---------------------------------------------------------------- merge partials
// grid (512, 8): x = qb*16+h, y = qrow-group. Thread: slot = t&15 owns
// d [slot*8, +8) (one uint4 = 8 fp16), qrow = y*16 + (t>>4). 16 consecutive
// lanes read 256B contiguous per qrow -> fully coalesced, 8x fewer instrs.
// Reference merge IN CHUNK ORDER: d = a + sE + 1e-10; o = o*(l_g/d) + ohat*sE/d.
__global__ __launch_bounds__(256) void attn_merge(const u16* __restrict__ part,
                                                  const float* __restrict__ ml,
                                                  u16* __restrict__ attn) {
    const int b = blockIdx.x;
    const int qb = b >> 4, h = b & 15;
    const int g = qb >> 3;
    const int t = threadIdx.x;
    const int slot = t & 15;
    const int qrow = blockIdx.y * 16 + (t >> 4);
    const int d0 = slot * 8;

    float o[8];
#pragma unroll
    for (int i = 0; i < 8; ++i) o[i] = 0.0f;
    float m_g = -1e30f, l_g = 0.0f;

    for (int c = 0; c <= g; ++c) {
        int u;
        if (c == g)      u = 48 + (7 - (qb & 7)) * 4 + g;
        else if (g == 1) u = qb - 8;
        else if (g == 2) u = 8 + (qb - 16) * 2 + c;
        else             u = 24 + (qb - 24) * 3 + c;
        const int tile = u * 16 + h;
        const float m_c = ml[(size_t)tile * 256 + qrow * 2];
        const float l_c = ml[(size_t)tile * 256 + qrow * 2 + 1];
        const float mn = fmaxf(m_g, m_c);
        const float a = l_g * __expf(m_g - mn);
        const float eC = __expf(m_c - mn);
        const float sE = l_c * eC;
        const float d = a + sE + 1e-10f;
        const float f_old = l_g / d;
        const float f_new = sE / d;
        union { u16 s[8]; uint4 v; } ld;
        ld.v = *(const uint4*)(part + (size_t)tile * 16384 + (size_t)qrow * 128 + d0);
#pragma unroll
        for (int jj = 0; jj < 8; ++jj)
            o[jj] = o[jj] * f_old + h2f(ld.s[jj]) * f_new;
        l_g = a + sE;
        m_g = mn;
    }

    union { u16 s[8]; uint4 v; } pk;
#pragma unroll
    for (int i = 0; i < 8; ++i) pk.s[i] = f2bf(o[i]);
    *(uint4*)(attn + (size_t)(qb * 128 + qrow) * 2048 + h * 128 + d0) = pk.v;
}

// ---------------------------------------------------------------- launch
extern "C" void kernel_launch(void* const* d_in, const int* in_sizes, int n_in,
                              void* d_out, int out_size, void* d_ws, size_t ws_size,
                              hipStream_t stream) {
    const float* X  = (const float*)d_in[0];
    const int* pos  = (const int*)d_in[1];
    const float* Wq = (const float*)d_in[2];
    const float* Wk = (const float*)d_in[3];
    const float* Wv = (const float*)d_in[4];
    const float* Wo = (const float*)d_in[5];
    float* out = (float*)d_out;
    char* ws = (char*)d_ws;

    u16*   part = (u16*)(ws);
    u16*   Xbf  = (u16*)(ws);                      // overlay (dead before part)
    u16*   Wt   = (u16*)(ws + 16777216);           // [3072][2048] overlay
    u16*   QKV  = (u16*)(ws + 41943040);
    u16*   attn = (u16*)(ws + 41943040);           // overlay QKV (dead after partials)
    u16*   Vt   = (u16*)(ws + 67108864);
    float* ml   = (float*)(ws + 71303168);
    u16*   Wot  = (u16*)(ws + 72613888);

    convert_f32_bf16<<<2048, 256, 0, stream>>>(X, Xbf);
    transpose_w4<<<dim3(80, 32), 256, 0, stream>>>(Wq, Wk, Wv, Wo, Wt, Wot);

    gemm_bt<u16><<<dim3(32, 24), 256, 0, stream>>>(Xbf, Wt, QKV, 4096, 3072, 2048);

    rope_vt_kernel<<<5632, 256, 0, stream>>>(QKV, Vt, pos);

    attn_partial<<<1280, 256, 0, stream>>>(QKV, Vt, part, ml);
    attn_merge<<<dim3(512, 8), 256, 0, stream>>>(part, ml, attn);

    gemm_bt64<float><<<dim3(32, 16), 256, 0, stream>>>(attn, Wot, out, 4096, 2048, 2048);
}

// Round 17
// 414.204 us; speedup vs baseline: 1.0600x; 1.0047x over previous
//
#include <hip/hip_runtime.h>
#include <cstdint>
#include <cstddef>

// B=1, S=4096, HIDDEN=2048, HEADS=16, KVH=4, HD=128, CHUNK=1024.
// FINAL (R23 = R20/R22, reproduced green at 416.1us twice; session 448->416).
// Config: BK=32-dbuf gemm1 (R19), BK=64-dbuf gemm2 (R20), R13-optimum attn
// (KVBLK=64, count-free fence pipeline), q-major part epilogue (R15/16),
// coalesced-vector merge (R16), vectorized fast-math rope (R13/R18).
// Structural plateau, not HW roofline (MfmaUtil ~21%): both next levers
// (8-wave attn restructure, 256^2 8-phase GEMM) are new sync templates
// requiring race screening (m152); this session's two novel sync attempts
// (R6, R10) both raced. Measured-and-rejected: T13 defer-rescale (raced x2),
// counted-vmcnt mid-fence (raced), setprio (null/neg), attn KVBLK=32 (+5us),
// prep fusion (noise), rope-into-gemm fusion (+23us).
//
// ws arena (bytes), liveness overlays:
//   part  @ 0          41,943,040   (overlays Xbf@0 16MB + Wt@16MB 12.6MB)
//   QKV   @ 41,943,040 25,165,824   ([4096][3072]: Q | K | V bf16)
//     attn @ 41,943,040 16,777,216  (overlay after partials done)
//   Vt    @ 67,108,864  4,194,304   ([kvh][128][4096] bf16)
//   ml    @ 71,303,168  1,310,720   (fp32 m,l per q-row per partial)
//   Wot   @ 72,613,888  8,388,608
//   total 81,002,496 (~77.3 MB)

typedef unsigned short u16;
typedef unsigned int u32;
typedef float f32x4 __attribute__((ext_vector_type(4)));
typedef __bf16 bf16x8 __attribute__((ext_vector_type(8)));

__device__ __forceinline__ u16 f2bf(float f) {
    union { float f; u32 u; } v; v.f = f;
    u32 u = v.u;
    u += 0x7fffu + ((u >> 16) & 1u);
    return (u16)(u >> 16);
}
__device__ __forceinline__ float bf2f(u16 b) {
    union { u32 u; float f; } v; v.u = ((u32)b) << 16;
    return v.f;
}
__device__ __forceinline__ u16 f2h(float f) {
    union { _Float16 h; u16 u; } v; v.h = (_Float16)f; return v.u;
}
__device__ __forceinline__ float h2f(u16 u) {
    union { u16 u; _Float16 h; } v; v.u = u; return (float)v.h;
}
// packed bf16 pair via native casts (compiler emits v_cvt_pk_bf16_f32, RNE)
__device__ __forceinline__ u32 pkbf(float lo, float hi) {
    union { __bf16 h[2]; u32 u; } v;
    v.h[0] = (__bf16)lo; v.h[1] = (__bf16)hi;
    return v.u;
}
// v_exp_f32 computes 2^x (single HW instruction; ISA §3)
__device__ __forceinline__ float exp2_hw(float x) {
    float r;
    asm("v_exp_f32 %0, %1" : "=v"(r) : "v"(x));
    return r;
}

__device__ __forceinline__ void load16_to_lds(const void* g, void* l) {
    __builtin_amdgcn_global_load_lds((const __attribute__((address_space(1))) u32*)g,
                                     (__attribute__((address_space(3))) u32*)l,
                                     16, 0, 0);
}

// Explicit pipeline fence: drain this wave's vmem (glds) + lds ops, then
// block barrier. sched_barrier(0) on both sides: nothing moves across.
#define PIPE_FENCE() do {                                        \
    __builtin_amdgcn_sched_barrier(0);                           \
    asm volatile("s_waitcnt vmcnt(0) lgkmcnt(0)" ::: "memory");  \
    __builtin_amdgcn_sched_barrier(0);                           \
    __builtin_amdgcn_s_barrier();                                \
    __builtin_amdgcn_sched_barrier(0);                           \
} while (0)

#define MFMA16(a, b, c) __builtin_amdgcn_mfma_f32_16x16x32_bf16((a), (b), (c), 0, 0, 0)

// ---------------------------------------------------------------- convert X
__global__ __launch_bounds__(256) void convert_f32_bf16(const float* __restrict__ X,
                                                        u16* __restrict__ Y) {
    const int base = (blockIdx.x * 1024 + threadIdx.x) * 4;
#pragma unroll
    for (int k = 0; k < 4; ++k) {
        const int i = base + k * 1024;
        const float4 v = *(const float4*)(X + i);
        union { u16 s[4]; uint2 u; } pk;
        pk.s[0] = f2bf(v.x); pk.s[1] = f2bf(v.y); pk.s[2] = f2bf(v.z); pk.s[3] = f2bf(v.w);
        *(uint2*)(Y + i) = pk.u;
    }
}

// -------------------------- fused transpose of all 4 weights -> bf16 [N][K]
// grid (80, 32): x<32 Wq->Wt, x<40 Wk->Wt+2048*2048, x<48 Wv->Wt+2560*2048,
// x>=48 Wo->Wot. Source is [K=2048][N] fp32.
__global__ __launch_bounds__(256) void transpose_w4(const float* __restrict__ Wq,
                                                    const float* __restrict__ Wk,
                                                    const float* __restrict__ Wv,
                                                    const float* __restrict__ Wo,
                                                    u16* __restrict__ Wt,
                                                    u16* __restrict__ Wot) {
    __shared__ float tile[64][65];
    const int bx = blockIdx.x;
    const float* W; u16* dst; int N, n0;
    if (bx < 32)      { W = Wq; dst = Wt;                          N = 2048; n0 = bx * 64; }
    else if (bx < 40) { W = Wk; dst = Wt + (size_t)2048 * 2048;    N = 512;  n0 = (bx - 32) * 64; }
    else if (bx < 48) { W = Wv; dst = Wt + (size_t)2560 * 2048;    N = 512;  n0 = (bx - 40) * 64; }
    else              { W = Wo; dst = Wot;                         N = 2048; n0 = (bx - 48) * 64; }
    const int k0 = blockIdx.y * 64;
    const int tc = threadIdx.x & 63, tr = threadIdx.x >> 6;
#pragma unroll
    for (int i = 0; i < 64; i += 4)
        tile[tc][tr + i] = W[(size_t)(k0 + tr + i) * N + n0 + tc];
    __syncthreads();
#pragma unroll
    for (int i = 0; i < 64; i += 4)
        dst[(size_t)(n0 + tr + i) * 2048 + k0 + tc] = f2bf(tile[tr + i][tc]);
}

// ---------------------------------------------------------------- GEMM C = A * Bt^T
__device__ __forceinline__ void store_out(float* p, float v) { *p = v; }
__device__ __forceinline__ void store_out(u16* p, float v) { *p = f2bf(v); }

// R19 variant: BK=32, double-buffered (2x8KB per matrix = 32KB LDS), prefetch
// stage(k+1); compute(k); ONE count-free PIPE_FENCE per K-step. (gemm1: 3 blk/CU)
template <typename OutT>
__global__ __launch_bounds__(256) void gemm_bt(const u16* __restrict__ A,
                                               const u16* __restrict__ Bt,
                                               OutT* __restrict__ C,
                                               int M, int N, int K) {
    __shared__ __align__(16) u16 sA[2][4096];   // 8KB each: 8 A-frags (16x32)
    __shared__ __align__(16) u16 sB[2][4096];   // 8KB each: 8 B-frags (16x32)
    const int t = threadIdx.x;
    const int lane = t & 63, w = t >> 6;
    const int quad = lane >> 4, l15 = lane & 15;
    const int m0 = blockIdx.x << 7, n0 = blockIdx.y << 7;
    const int wr4 = (w >> 1) * 4, wc4 = (w & 1) * 4;
    f32x4 acc[4][4] = {};

    // prologue: stage K-tile 0 into buf[1]
#pragma unroll
    for (int r = 0; r < 2; ++r) {
        const int f = w * 2 + r;
        load16_to_lds(A + (size_t)(m0 + f * 16 + l15) * K + quad * 8, sA[1] + f * 512);
        load16_to_lds(Bt + (size_t)(n0 + f * 16 + l15) * K + quad * 8, sB[1] + f * 512);
    }
    PIPE_FENCE();          // tile 0 landed, visible to all waves

    int cur = 1;
    const int nk = K >> 5;
    for (int kt = 0; kt < nk; ++kt) {
        if (kt + 1 < nk) {
            const int koff = (kt + 1) << 5;
#pragma unroll
            for (int r = 0; r < 2; ++r) {
                const int f = w * 2 + r;
                load16_to_lds(A + (size_t)(m0 + f * 16 + l15) * K + koff + quad * 8,
                              sA[cur ^ 1] + f * 512);
                load16_to_lds(Bt + (size_t)(n0 + f * 16 + l15) * K + koff + quad * 8,
                              sB[cur ^ 1] + f * 512);
            }
        }
        const u16* bA = sA[cur];
        const u16* bB = sB[cur];
        bf16x8 af[4], bb[4];
#pragma unroll
        for (int i = 0; i < 4; ++i)
            af[i] = *(const bf16x8*)(bA + (wr4 + i) * 512 + lane * 8);
#pragma unroll
        for (int j = 0; j < 4; ++j)
            bb[j] = *(const bf16x8*)(bB + (wc4 + j) * 512 + lane * 8);
#pragma unroll
        for (int i = 0; i < 4; ++i)
#pragma unroll
            for (int j = 0; j < 4; ++j)
                acc[i][j] = MFMA16(af[i], bb[j], acc[i][j]);
        if (kt + 1 < nk) {
            PIPE_FENCE();
            cur ^= 1;
        }
    }
#pragma unroll
    for (int i = 0; i < 4; ++i)
#pragma unroll
        for (int j = 0; j < 4; ++j) {
            const int row = m0 + (w >> 1) * 64 + i * 16 + quad * 4;
            const int col = n0 + (w & 1) * 64 + j * 16 + l15;
#pragma unroll
            for (int r = 0; r < 4; ++r)
                store_out(C + (size_t)(row + r) * N + col, acc[i][j][r]);
        }
}

// R20 variant: BK=64, double-buffered (2x16KB per matrix = 64KB LDS -> 2 blk/CU),
// same prefetch + count-free fence. 32 MFMA + 16 ds_read per K-step: compute
// phase (~500cy) covers glds flight; half the fences of BK=32. For gemm2 whose
// grid (512 blocks) is exactly 2/CU — zero occupancy loss.
template <typename OutT>
__global__ __launch_bounds__(256, 2) void gemm_bt64(const u16* __restrict__ A,
                                                    const u16* __restrict__ Bt,
                                                    OutT* __restrict__ C,
                                                    int M, int N, int K) {
    __shared__ __align__(16) u16 sA[2][8192];   // 16KB each: 16 A-frags (16x32)
    __shared__ __align__(16) u16 sB[2][8192];
    const int t = threadIdx.x;
    const int lane = t & 63, w = t >> 6;
    const int quad = lane >> 4, l15 = lane & 15;
    const int m0 = blockIdx.x << 7, n0 = blockIdx.y << 7;
    const int wr4 = (w >> 1) * 4, wc4 = (w & 1) * 4;
    f32x4 acc[4][4] = {};

    // prologue: stage K-tile 0 (64 wide) into buf[1]
#pragma unroll
    for (int r = 0; r < 2; ++r) {
        const int f = w * 2 + r;
#pragma unroll
        for (int kc = 0; kc < 2; ++kc) {
            load16_to_lds(A + (size_t)(m0 + f * 16 + l15) * K + kc * 32 + quad * 8,
                          sA[1] + (f * 2 + kc) * 512);
            load16_to_lds(Bt + (size_t)(n0 + f * 16 + l15) * K + kc * 32 + quad * 8,
                          sB[1] + (f * 2 + kc) * 512);
        }
    }
    PIPE_FENCE();          // tile 0 landed

    int cur = 1;
    const int nk = K >> 6;
    for (int kt = 0; kt < nk; ++kt) {
        if (kt + 1 < nk) {
            const int koff = (kt + 1) << 6;
#pragma unroll
            for (int r = 0; r < 2; ++r) {
                const int f = w * 2 + r;
#pragma unroll
                for (int kc = 0; kc < 2; ++kc) {
                    load16_to_lds(A + (size_t)(m0 + f * 16 + l15) * K + koff + kc * 32 + quad * 8,
                                  sA[cur ^ 1] + (f * 2 + kc) * 512);
                    load16_to_lds(Bt + (size_t)(n0 + f * 16 + l15) * K + koff + kc * 32 + quad * 8,
                                  sB[cur ^ 1] + (f * 2 + kc) * 512);
                }
            }
        }
        const u16* bA = sA[cur];
        const u16* bB = sB[cur];
#pragma unroll
        for (int kc = 0; kc < 2; ++kc) {
            bf16x8 af[4], bb[4];
#pragma unroll
            for (int i = 0; i < 4; ++i)
                af[i] = *(const bf16x8*)(bA + ((wr4 + i) * 2 + kc) * 512 + lane * 8);
#pragma unroll
            for (int j = 0; j < 4; ++j)
                bb[j] = *(const bf16x8*)(bB + ((wc4 + j) * 2 + kc) * 512 + lane * 8);
#pragma unroll
            for (int i = 0; i < 4; ++i)
#pragma unroll
                for (int j = 0; j < 4; ++j)
                    acc[i][j] = MFMA16(af[i], bb[j], acc[i][j]);
        }
        if (kt + 1 < nk) {
            PIPE_FENCE();
            cur ^= 1;
        }
    }
#pragma unroll
    for (int i = 0; i < 4; ++i)
#pragma unroll
        for (int j = 0; j < 4; ++j) {
            const int row = m0 + (w >> 1) * 64 + i * 16 + quad * 4;
            const int col = n0 + (w & 1) * 64 + j * 16 + l15;
#pragma unroll
            for (int r = 0; r < 4; ++r)
                store_out(C + (size_t)(row + r) * N + col, acc[i][j][r]);
        }
}

// --------------------------------------- fused YaRN RoPE (in place) + V transpose
// R18: vectorized rope — each thread handles 4 rotation pairs (uint2 at
// i..i+3 and i+64..i+67). blocks 0..5119: rope on QKV. blocks 5120..5631:
// transpose V (cols 2560+) -> Vt. Fast-math trig (R13).
__global__ __launch_bounds__(256) void rope_vt_kernel(u16* __restrict__ QKV,
                                                      u16* __restrict__ Vt,
                                                      const int* __restrict__ pos_ids) {
    __shared__ u16 tile[64 * 72];
    if (blockIdx.x >= 5120) {
        const int b = blockIdx.x - 5120;            // (64, 2, 4) linearized
        const int k0 = (b & 63) * 64, d0 = ((b >> 6) & 1) * 64, kvh = b >> 7;
        const int t = threadIdx.x;
#pragma unroll
        for (int k = 0; k < 4; ++k) {
            const int u = t + k * 256;
            const int key = u >> 4, dg = u & 15;
            const uint2 v = *(const uint2*)(QKV + (size_t)(k0 + key) * 3072 + 2560 + kvh * 128 + d0 + dg * 4);
            *(uint2*)(tile + key * 72 + dg * 4) = v;
        }
        __syncthreads();
#pragma unroll
        for (int k = 0; k < 4; ++k) {
            const int u = t + k * 256;
            const int d = u >> 4, kg = u & 15;
            union { u16 s[4]; uint2 v; } pk;
#pragma unroll
            for (int i = 0; i < 4; ++i) pk.s[i] = tile[(kg * 4 + i) * 72 + d];
            *(uint2*)(Vt + (size_t)(kvh * 128 + d0 + d) * 4096 + k0 + kg * 4) = pk.v;
        }
        return;
    }
    const int u = blockIdx.x * 256 + threadIdx.x;
    const int NQ4 = 4096 * 16 * 16;                 // Q rope threads (4 pairs each)
    u16* p;
    int s, i4;
    if (u < NQ4) {
        s = u >> 8;
        const int rest = u & 255;
        const int h = rest >> 4;
        i4 = rest & 15;
        p = QKV + (size_t)s * 3072 + h * 128 + i4 * 4;
    } else {
        const int u2 = u - NQ4;
        s = u2 >> 6;
        const int rest = u2 & 63;
        const int h = rest >> 4;
        i4 = rest & 15;
        p = QKV + (size_t)s * 3072 + 2048 + h * 128 + i4 * 4;
    }
    const float pf = (float)pos_ids[s];
    const float MS = 1.2772588722239781f;
    union { u16 s4[4]; uint2 v; } lo, hi, so, sh;
    lo.v = *(const uint2*)(p);                      // x1: i..i+3
    hi.v = *(const uint2*)(p + 64);                 // x2: i+64..i+67
#pragma unroll
    for (int e = 0; e < 4; ++e) {
        const float fi = (float)(i4 * 4 + e);
        // 500000^(-fi/64) = exp2(-fi*log2(500000)/64); log2(5e5)/64 = 0.29580637
        const float inv_ex = exp2_hw(fi * -0.29580637f);
        const float inv_in = inv_ex * (1.0f / 16.0f);
        const float sm = fminf(fmaxf((fi - 18.0f) * (1.0f / 17.0f), 0.0f), 1.0f);
        const float inv = (1.0f - sm) * inv_in + sm * inv_ex;
        const float ph = pf * inv;                  // <= ~256 rad (~41 rev)
        const float cs = __cosf(ph) * MS, sn = __sinf(ph) * MS;
        const float x1 = bf2f(lo.s4[e]), x2 = bf2f(hi.s4[e]);
        so.s4[e] = f2bf(x1 * cs - x2 * sn);
        sh.s4[e] = f2bf(x2 * cs + x1 * sn);
    }
    *(uint2*)(p) = so.v;
    *(uint2*)(p + 64) = sh.v;
}

// ---------------------------------------------------------------- attention partials
// grid 1280 (bid = u*16 + h; 80 units/head, longest-first). Block: 128 q rows x one
// 1024-chunk, KVBLK=64 (R13 optimum). Wave w owns q-cols [w*32,+32): S^T = K*Q^T
// (B=Q in regs, af[2][4]), O^T = V^T*P^T. R9 sync: ping-pong K/V, stage(j+1);
// compute(j); PIPE_FENCE (count-free). Epilogue: part q-major [tile][q][d] fp16.
__device__ __forceinline__ void stage_kv(const u16* __restrict__ QKV,
                                         const u16* __restrict__ Vt,
                                         int kt0, int kvh, int w, int l15, int quad,
                                         u16* bK, u16* bV) {
    const u16* gk = QKV + (size_t)(kt0 + w * 16 + l15) * 3072 + 2048 + kvh * 128 + quad * 8;
#pragma unroll
    for (int kc = 0; kc < 4; ++kc)
        load16_to_lds(gk + kc * 32, bK + (w * 4 + kc) * 512);
#pragma unroll
    for (int r = 0; r < 4; ++r) {
        const int dt = w * 2 + (r >> 1), ks = r & 1;
        load16_to_lds(Vt + (size_t)(kvh * 128 + dt * 16 + l15) * 4096 + kt0 + ks * 32 + quad * 8,
                      bV + (dt * 2 + ks) * 512);
    }
}

__global__ __launch_bounds__(256, 2) void attn_partial(const u16* __restrict__ QKV,
                                                       const u16* __restrict__ Vt,
                                                       u16* __restrict__ part,
                                                       float* __restrict__ ml) {
    __shared__ __align__(16) u16 sK[2][8192];   // ping-pong K frags (buf0 also Q stage w0-1)
    __shared__ __align__(16) u16 sV[2][8192];   // ping-pong V^T frags (buf0 also Q stage w2-3)

    const int t = threadIdx.x;
    const int lane = t & 63, w = t >> 6;
    const int quad = lane >> 4, l15 = lane & 15;
    const int bid = blockIdx.x;
    const int u = bid >> 4, h = bid & 15, kvh = h >> 2;

    // unit decode (longest-first): u<48 full chunks, u>=48 diagonal by desc length
    int qb, c;
    if (u < 8)       { qb = 8 + u; c = 0; }
    else if (u < 24) { const int r = u - 8;  qb = 16 + (r >> 1); c = r & 1; }
    else if (u < 48) { const int r = u - 24; const int q3 = r / 3; qb = 24 + q3; c = r - q3 * 3; }
    else             { const int r = u - 48; const int k = r >> 2; const int g0 = r & 3;
                       qb = g0 * 8 + (7 - k); c = g0; }
    const int g = qb >> 3;
    const int q0 = qb << 7, kv0 = c << 10;
    const int jmax = (c == g) ? (2 * (qb & 7) + 2) : 16;

    // stage Q into buf0 (waves 0-1 -> sK[0], waves 2-3 -> sV[0])
    {
        u16* dst0 = (w < 2) ? sK[0] : sV[0];
        const int fbase = (w & 1) * 8;
#pragma unroll
        for (int idx = 0; idx < 8; ++idx) {
            const int qg = idx >> 2, kc = idx & 3;
            load16_to_lds(QKV + (size_t)(q0 + w * 32 + qg * 16 + l15) * 3072 + h * 128 + kc * 32 + quad * 8,
                          dst0 + (fbase + idx) * 512);
        }
    }
    PIPE_FENCE();          // Q glds drained + barrier: Q visible to all waves
    bf16x8 af[2][4];
    {
        const u16* src0 = (w < 2) ? sK[0] : sV[0];
        const int fbase = (w & 1) * 8;
#pragma unroll
        for (int qg = 0; qg < 2; ++qg)
#pragma unroll
            for (int kc = 0; kc < 4; ++kc)
                af[qg][kc] = *(const bf16x8*)(src0 + (fbase + qg * 4 + kc) * 512 + lane * 8);
    }
    // prefetch tile 0 into buf1 (issued now; drained by the fence below)
    stage_kv(QKV, Vt, kv0, kvh, w, l15, quad, sK[1], sV[1]);
    PIPE_FENCE();          // Q reg-reads drained (lgkm), tile0 landed (vmcnt), barrier

    float m_c[2] = {-1e30f, -1e30f}, l_c[2] = {0.0f, 0.0f};
    f32x4 o_c[8][2] = {};
    const float SCALE = 0.08838834764831845f;            // 128^-0.5
    const float LOG2E = 1.4426950408889634f;
    const float CS = SCALE * LOG2E;                      // fold scale into exp2 fma

    // in-register P^T redistribution constants (loop-invariant)
    const int srcLo = ((quad & 1) << 5) | l15;   // source lane for B-frag elems 0-3
    const int srcHi = srcLo | 16;                // source lane for B-frag elems 4-7
    const bool selB = (quad & 2) != 0;           // j4 = 2ks+1 when target quad >= 2

    int cur = 1;                                 // tile j lives in buf[cur]
    for (int j = 0; j < jmax; ++j) {
        // issue stage of tile j+1 into the other buffer; flies during compute of j
        if (j + 1 < jmax)
            stage_kv(QKV, Vt, kv0 + ((j + 1) << 6), kvh, w, l15, quad,
                     sK[cur ^ 1], sV[cur ^ 1]);

        const u16* bK = sK[cur];
        const u16* bV = sV[cur];
        const int kt0 = kv0 + (j << 6);

        // S^T = K * Q^T : 16 K-frag reads, 32 MFMA (reuse across qg). RAW scores.
        f32x4 sacc[4][2] = {};
#pragma unroll
        for (int j4 = 0; j4 < 4; ++j4)
#pragma unroll
            for (int kc = 0; kc < 4; ++kc) {
                const bf16x8 kf = *(const bf16x8*)(bK + (j4 * 4 + kc) * 512 + lane * 8);
                sacc[j4][0] = MFMA16(kf, af[0][kc], sacc[j4][0]);
                sacc[j4][1] = MFMA16(kf, af[1][kc], sacc[j4][1]);
            }

        // causal mask in raw domain (only last two tiles of diagonal chunk)
        const bool diag = (c == g) && ((j >> 1) == (qb & 7));
        if (diag) {
#pragma unroll
            for (int j4 = 0; j4 < 4; ++j4)
#pragma unroll
                for (int qg = 0; qg < 2; ++qg) {
                    const int qrow = q0 + w * 32 + qg * 16 + l15;
#pragma unroll
                    for (int r = 0; r < 4; ++r) {
                        const int key = kt0 + j4 * 16 + quad * 4 + r;
                        if (key > qrow) sacc[j4][qg][r] = -1e30f;
                    }
                }
        }

        // online softmax + in-register P pack/redistribute, per qg
        bf16x8 pf[2][2];
#pragma unroll
        for (int qg = 0; qg < 2; ++qg) {
            // tree max over 16 raw scores
            f32x4 v01, v23;
#pragma unroll
            for (int r = 0; r < 4; ++r) {
                v01[r] = fmaxf(sacc[0][qg][r], sacc[1][qg][r]);
                v23[r] = fmaxf(sacc[2][qg][r], sacc[3][qg][r]);
            }
            float mx = fmaxf(fmaxf(fmaxf(v01[0], v01[1]), fmaxf(v01[2], v01[3])),
                             fmaxf(fmaxf(v23[0], v23[1]), fmaxf(v23[2], v23[3])));
            mx = fmaxf(mx, __shfl_xor(mx, 16, 64));
            mx = fmaxf(mx, __shfl_xor(mx, 32, 64));
            const float mn = fmaxf(m_c[qg], mx * SCALE);         // scaled domain
            const float alpha = exp2_hw((m_c[qg] - mn) * LOG2E);
            const float kk = -mn * LOG2E;
#pragma unroll
            for (int j4 = 0; j4 < 4; ++j4)
#pragma unroll
                for (int r = 0; r < 4; ++r)
                    sacc[j4][qg][r] = exp2_hw(fmaf(sacc[j4][qg][r], CS, kk));
            const f32x4 pv = (sacc[0][qg] + sacc[1][qg]) + (sacc[2][qg] + sacc[3][qg]);
            float ps = (pv[0] + pv[1]) + (pv[2] + pv[3]);
            ps += __shfl_xor(ps, 16, 64);
            ps += __shfl_xor(ps, 32, 64);
            l_c[qg] = l_c[qg] * alpha + ps;
            m_c[qg] = mn;
#pragma unroll
            for (int dt = 0; dt < 8; ++dt) o_c[dt][qg] *= alpha;

            // pack pe -> bf16 pairs per j4 (source fragment layout)
            u32 pk[4][2];
#pragma unroll
            for (int j4 = 0; j4 < 4; ++j4) {
                pk[j4][0] = pkbf(sacc[j4][qg][0], sacc[j4][qg][1]);
                pk[j4][1] = pkbf(sacc[j4][qg][2], sacc[j4][qg][3]);
            }
            // redistribute to PV B-frag: lane(quad,q) needs keys ks*32+quad*8+e
            // from source lanes (quad&1)*32+l15 (+16), j4 = 2ks + (quad>>1).
#pragma unroll
            for (int ks = 0; ks < 2; ++ks) {
                union { u32 wd[4]; bf16x8 v; } bu;
                const u32 a0 = pk[2 * ks][0], a1 = pk[2 * ks][1];
                const u32 b0 = pk[2 * ks + 1][0], b1 = pk[2 * ks + 1][1];
                const u32 xa0 = (u32)__shfl((int)a0, srcLo, 64);
                const u32 xb0 = (u32)__shfl((int)b0, srcLo, 64);
                bu.wd[0] = selB ? xb0 : xa0;
                const u32 xa1 = (u32)__shfl((int)a1, srcLo, 64);
                const u32 xb1 = (u32)__shfl((int)b1, srcLo, 64);
                bu.wd[1] = selB ? xb1 : xa1;
                const u32 ya0 = (u32)__shfl((int)a0, srcHi, 64);
                const u32 yb0 = (u32)__shfl((int)b0, srcHi, 64);
                bu.wd[2] = selB ? yb0 : ya0;
                const u32 ya1 = (u32)__shfl((int)a1, srcHi, 64);
                const u32 yb1 = (u32)__shfl((int)b1, srcHi, 64);
                bu.wd[3] = selB ? yb1 : ya1;
                pf[qg][ks] = bu.v;
            }
        }

        // O^T += V^T * P^T : 16 V-frag reads, 32 MFMA (reuse across qg)
#pragma unroll
        for (int ks = 0; ks < 2; ++ks) {
#pragma unroll
            for (int dt = 0; dt < 8; ++dt) {
                const bf16x8 vf = *(const bf16x8*)(bV + (dt * 2 + ks) * 512 + lane * 8);
                o_c[dt][0] = MFMA16(vf, pf[0][ks], o_c[dt][0]);
                o_c[dt][1] = MFMA16(vf, pf[1][ks], o_c[dt][1]);
            }
        }

        // end-of-tile fence: tile j+1 glds landed; all waves done reading buf[cur]
        if (j + 1 < jmax) {
            PIPE_FENCE();
            cur ^= 1;
        }
    }

    // epilogue: part q-major [bid][q=128][d=128] fp16 (8B vector stores),
    // ml [bid][q=128][2] fp32
#pragma unroll
    for (int qg = 0; qg < 2; ++qg) {
        const float invl = 1.0f / l_c[qg];
        const int q = w * 32 + qg * 16 + l15;
        u16* pbase = part + (size_t)bid * 16384 + (size_t)q * 128 + quad * 4;
#pragma unroll
        for (int dt = 0; dt < 8; ++dt) {
            union { u16 s[4]; uint2 v; } pk4;
#pragma unroll
            for (int r = 0; r < 4; ++r) pk4.s[r] = f2h(o_c[dt][qg][r] * invl);
            *(uint2*)(pbase + dt * 16) = pk4.v;
        }
        if (quad == 0) {
            ml[(size_t)bid * 256 + q * 2] = m_c[qg];
            ml[(size_t)bid * 256 + q * 2 + 1] = l_c[qg];
        }
    }
}

// ---------------------------------------------------------------- merge partials
// grid (512, 8): x = qb*16+h, y = qrow-group. Thread: slot = t&15 owns
// d [slot*8, +8) (one uint4 = 8 fp16), qrow = y*16 + (t>>4). 16 consecutive
// lanes read 256B contiguous per qrow -> fully coalesced, 8x fewer instrs.
// Reference merge IN CHUNK ORDER: d = a + sE + 1e-10; o = o*(l_g/d) + ohat*sE/d.
__global__ __launch_bounds__(256) void attn_merge(const u16* __restrict__ part,
                                                  const float* __restrict__ ml,
                                                  u16* __restrict__ attn) {
    const int b = blockIdx.x;
    const int qb = b >> 4, h = b & 15;
    const int g = qb >> 3;
    const int t = threadIdx.x;
    const int slot = t & 15;
    const int qrow = blockIdx.y * 16 + (t >> 4);
    const int d0 = slot * 8;

    float o[8];
#pragma unroll
    for (int i = 0; i < 8; ++i) o[i] = 0.0f;
    float m_g = -1e30f, l_g = 0.0f;

    for (int c = 0; c <= g; ++c) {
        int u;
        if (c == g)      u = 48 + (7 - (qb & 7)) * 4 + g;
        else if (g == 1) u = qb - 8;
        else if (g == 2) u = 8 + (qb - 16) * 2 + c;
        else             u = 24 + (qb - 24) * 3 + c;
        const int tile = u * 16 + h;
        const float m_c = ml[(size_t)tile * 256 + qrow * 2];
        const float l_c = ml[(size_t)tile * 256 + qrow * 2 + 1];
        const float mn = fmaxf(m_g, m_c);
        const float a = l_g * __expf(m_g - mn);
        const float eC = __expf(m_c - mn);
        const float sE = l_c * eC;
        const float d = a + sE + 1e-10f;
        const float f_old = l_g / d;
        const float f_new = sE / d;
        union { u16 s[8]; uint4 v; } ld;
        ld.v = *(const uint4*)(part + (size_t)tile * 16384 + (size_t)qrow * 128 + d0);
#pragma unroll
        for (int jj = 0; jj < 8; ++jj)
            o[jj] = o[jj] * f_old + h2f(ld.s[jj]) * f_new;
        l_g = a + sE;
        m_g = mn;
    }

    union { u16 s[8]; uint4 v; } pk;
#pragma unroll
    for (int i = 0; i < 8; ++i) pk.s[i] = f2bf(o[i]);
    *(uint4*)(attn + (size_t)(qb * 128 + qrow) * 2048 + h * 128 + d0) = pk.v;
}

// ---------------------------------------------------------------- launch
extern "C" void kernel_launch(void* const* d_in, const int* in_sizes, int n_in,
                              void* d_out, int out_size, void* d_ws, size_t ws_size,
                              hipStream_t stream) {
    const float* X  = (const float*)d_in[0];
    const int* pos  = (const int*)d_in[1];
    const float* Wq = (const float*)d_in[2];
    const float* Wk = (const float*)d_in[3];
    const float* Wv = (const float*)d_in[4];
    const float* Wo = (const float*)d_in[5];
    float* out = (float*)d_out;
    char* ws = (char*)d_ws;

    u16*   part = (u16*)(ws);
    u16*   Xbf  = (u16*)(ws);                      // overlay (dead before part)
    u16*   Wt   = (u16*)(ws + 16777216);           // [3072][2048] overlay
    u16*   QKV  = (u16*)(ws + 41943040);
    u16*   attn = (u16*)(ws + 41943040);           // overlay QKV (dead after partials)
    u16*   Vt   = (u16*)(ws + 67108864);
    float* ml   = (float*)(ws + 71303168);
    u16*   Wot  = (u16*)(ws + 72613888);

    convert_f32_bf16<<<2048, 256, 0, stream>>>(X, Xbf);
    transpose_w4<<<dim3(80, 32), 256, 0, stream>>>(Wq, Wk, Wv, Wo, Wt, Wot);

    gemm_bt<u16><<<dim3(32, 24), 256, 0, stream>>>(Xbf, Wt, QKV, 4096, 3072, 2048);

    rope_vt_kernel<<<5632, 256, 0, stream>>>(QKV, Vt, pos);

    attn_partial<<<1280, 256, 0, stream>>>(QKV, Vt, part, ml);
    attn_merge<<<dim3(512, 8), 256, 0, stream>>>(part, ml, attn);

    gemm_bt64<float><<<dim3(32, 16), 256, 0, stream>>>(attn, Wot, out, 4096, 2048, 2048);
}